// Round 13
// baseline (265.630 us; speedup 1.0000x reference)
//
#include <hip/hip_runtime.h>
#include <math.h>

constexpr int NN    = 4096;
constexpr int INDIM = 256;
constexpr int HID   = 64;
constexpr int HEADS = 8;
constexpr int HH    = HID * HEADS;  // 512
constexpr int DMAX  = 256;          // deg cap: Binomial(4096,0.01) mean 42
constexpr int PROJ_BLOCKS = 2048;   // 8 heads x 256 sixteen-row tiles

typedef float        vfloat4 __attribute__((ext_vector_type(4)));
typedef unsigned int vuint4  __attribute__((ext_vector_type(4)));

__device__ __forceinline__ float gelu_exact(float x) {
    return 0.5f * x * (1.0f + erff(x * 0.70710678118654752f));
}

__device__ __forceinline__ float wave_reduce64(float v) {
    v += __shfl_xor(v, 32); v += __shfl_xor(v, 16); v += __shfl_xor(v, 8);
    v += __shfl_xor(v, 4);  v += __shfl_xor(v, 2);  v += __shfl_xor(v, 1);
    return v;
}

// ---------------------------------------------------------------------------
// prep: grid-partitioned fusion of proj (blocks 0..2047) and detect+CSR
// (blocks 2048..6143). R12 post-mortem: proj at 512 blocks = 2 waves/SIMD
// couldn't hide global-load latency (VALUBusy 30%). This version: LDS-FREE
// proj, 2048 blocks (16-row tiles, 1x4 microtile), no barriers in the proj
// path -> occupancy capped only by wave slots (8 blocks/CU = 32 waves/CU).
// B (64KB/head) served from L1/L2 with 16-lane broadcast; A rows 16B loads.
// Per thread: 1024 FMA, 5 loads per 16 FMA -> VALU-bound by construction.
// ---------------------------------------------------------------------------
__global__ __launch_bounds__(256) void prep_kernel(
    const void* __restrict__ adjv,
    const float* __restrict__ A, const float* __restrict__ B,
    float* __restrict__ projT,
    unsigned short* __restrict__ nbr_g, int* __restrict__ deg_g) {
    __shared__ int wsum[4], u8w[4]; // csr path only (32B)
    const int pb = blockIdx.x, t = threadIdx.x;
    const int wv = t >> 6, lane = t & 63;

    if (pb < PROJ_BLOCKS) {
        // ================= proj path (LDS-free, barrier-free) =================
        const int bx = pb & 7;          // head
        const int by = pb >> 3;         // 16-row tile (0..255)
        const int tx = t & 15, ty = t >> 4;
        const int row = by * 16 + ty;
        const float* ap = A + (size_t)row * INDIM;
        const float* bp = B + bx * 64 + tx * 4;
        float a0 = 0.f, a1 = 0.f, a2 = 0.f, a3 = 0.f;
        #pragma unroll 4
        for (int k = 0; k < INDIM; k += 4) {
            const float4 av = *reinterpret_cast<const float4*>(ap + k);
            const float4 b0 = *reinterpret_cast<const float4*>(bp + (size_t)(k + 0) * HH);
            const float4 b1 = *reinterpret_cast<const float4*>(bp + (size_t)(k + 1) * HH);
            const float4 b2 = *reinterpret_cast<const float4*>(bp + (size_t)(k + 2) * HH);
            const float4 b3 = *reinterpret_cast<const float4*>(bp + (size_t)(k + 3) * HH);
            a0 += av.x * b0.x + av.y * b1.x + av.z * b2.x + av.w * b3.x;
            a1 += av.x * b0.y + av.y * b1.y + av.z * b2.y + av.w * b3.y;
            a2 += av.x * b0.z + av.y * b1.z + av.z * b2.z + av.w * b3.z;
            a3 += av.x * b0.w + av.y * b1.w + av.z * b2.w + av.w * b3.w;
        }
        // projT[head=bx][node=row][dim=tx*4..]
        float4 o = {a0, a1, a2, a3};
        *reinterpret_cast<float4*>(
            projT + ((size_t)bx * NN + row) * HID + tx * 4) = o;
    } else {
        // ================= detect + csr path =================
        const int n = pb - PROJ_BLOCKS;
        // dtype detection on the buffer's first 4KB (16B/thread, L2-hot;
        // identical bytes for every block -> deterministic outcome)
        const vuint4 pw = __builtin_nontemporal_load(
            reinterpret_cast<const vuint4*>(adjv) + t);
        int u8loc = 0;
        #pragma unroll
        for (int a = 0; a < 4; ++a) {
            const unsigned w = pw[a];
            if (((w & ~0x01010101u) == 0u) && ((w & 0xFFFFFF00u) != 0u)) u8loc = 1;
        }
        const unsigned long long wb = __ballot(u8loc);
        if (lane == 0) u8w[wv] = (wb != 0ull);
        __syncthreads();
        const bool isU8 = (u8w[0] | u8w[1] | u8w[2] | u8w[3]) != 0;

        unsigned int nzmask = 0;  // bit j = element 16t+j of row n nonzero
        if (isU8) {
            const vuint4 r = __builtin_nontemporal_load(
                reinterpret_cast<const vuint4*>(
                    (const unsigned char*)adjv + (size_t)n * NN + 16 * t));
            #pragma unroll
            for (int a = 0; a < 4; ++a)
                #pragma unroll
                for (int j = 0; j < 4; ++j)
                    if ((r[a] >> (8 * j)) & 0xFFu) nzmask |= 1u << (a * 4 + j);
        } else {
            const vuint4* p = reinterpret_cast<const vuint4*>(
                (const unsigned int*)adjv + (size_t)n * NN + 16 * t);
            #pragma unroll
            for (int a = 0; a < 4; ++a) {
                const vuint4 r = __builtin_nontemporal_load(p + a);
                if (r[0]) nzmask |= 1u << (a * 4 + 0);
                if (r[1]) nzmask |= 1u << (a * 4 + 1);
                if (r[2]) nzmask |= 1u << (a * 4 + 2);
                if (r[3]) nzmask |= 1u << (a * 4 + 3);
            }
        }
        const int c = __popc(nzmask);
        int x = c;  // wave-inclusive prefix scan
        #pragma unroll
        for (int d = 1; d < 64; d <<= 1) {
            int y = __shfl_up(x, d);
            if (lane >= d) x += y;
        }
        if (lane == 63) wsum[wv] = x;
        __syncthreads();
        int base = 0;
        #pragma unroll
        for (int i = 0; i < 4; ++i)
            if (i < wv) base += wsum[i];
        const int deg = min(wsum[0] + wsum[1] + wsum[2] + wsum[3], DMAX);
        if (t == 0) deg_g[n] = deg;
        int o = base + x - c;
        unsigned int mm = nzmask;
        while (mm) {
            const int j = __ffs(mm) - 1;
            mm &= mm - 1;
            if (o < DMAX) nbr_g[(size_t)n * DMAX + o] = (unsigned short)(16 * t + j);
            ++o;
        }
    }
}

// ---------------------------------------------------------------------------
// Head-split sparse GAT attention. Block b: head = b&7 (round-robin dispatch
// over 8 XCDs -> each XCD gathers from ONE head's 1MB table, L2-resident),
// 4 nodes (one per wave). Group g=lane>>3 handles neighbors c0+g; dims
// dl=8*(lane&7).. No-max softmax (logits bounded, rows ~N(0,1)).
// ---------------------------------------------------------------------------
__global__ __launch_bounds__(256) void attn_kernel(
    const float* __restrict__ projT,
    const unsigned short* __restrict__ nbr_g, const int* __restrict__ deg_g,
    float* __restrict__ attended) {
    __shared__ unsigned short nl[4][DMAX];   // 2KB: per-wave CSR row
    const int b = blockIdx.x, t = threadIdx.x;
    const int wv = t >> 6, lane = t & 63;
    const int h = b & 7;
    const int n = (b >> 3) * 4 + wv;
    const int deg = deg_g[n];

    *reinterpret_cast<ushort4*>(&nl[wv][lane * 4]) =
        *reinterpret_cast<const ushort4*>(nbr_g + (size_t)n * DMAX + lane * 4);

    const float* tab = projT + (size_t)h * NN * HID;
    const int g = lane >> 3, dl = (lane & 7) * 8;

    float q[8];
    {
        const float4 a = *reinterpret_cast<const float4*>(tab + (size_t)n * HID + dl);
        const float4 bq = *reinterpret_cast<const float4*>(tab + (size_t)n * HID + dl + 4);
        q[0] = a.x;  q[1] = a.y;  q[2] = a.z;  q[3] = a.w;
        q[4] = bq.x; q[5] = bq.y; q[6] = bq.z; q[7] = bq.w;
    }

    float l = 0.0f;
    float acc[8] = {0.f, 0.f, 0.f, 0.f, 0.f, 0.f, 0.f, 0.f};
    for (int c0 = 0; c0 < deg; c0 += 8) {
        const int c = c0 + g;
        const int idx = nl[wv][min(c, deg - 1)];
        const float* kp = tab + (size_t)idx * HID + dl;
        const float4 ka = *reinterpret_cast<const float4*>(kp);
        const float4 kb = *reinterpret_cast<const float4*>(kp + 4);
        float kf[8] = {ka.x, ka.y, ka.z, ka.w, kb.x, kb.y, kb.z, kb.w};
        float s = q[0]*kf[0] + q[1]*kf[1] + q[2]*kf[2] + q[3]*kf[3] +
                  q[4]*kf[4] + q[5]*kf[5] + q[6]*kf[6] + q[7]*kf[7];
        s += __shfl_xor(s, 1); s += __shfl_xor(s, 2); s += __shfl_xor(s, 4);
        const float w = (c < deg) ? expf(s * 0.125f) : 0.0f;  // 1/sqrt(64)
        l += w;
        #pragma unroll
        for (int i = 0; i < 8; ++i) acc[i] += w * kf[i];
    }
    l += __shfl_xor(l, 8); l += __shfl_xor(l, 16); l += __shfl_xor(l, 32);
    #pragma unroll
    for (int i = 0; i < 8; ++i) {
        acc[i] += __shfl_xor(acc[i], 8);
        acc[i] += __shfl_xor(acc[i], 16);
        acc[i] += __shfl_xor(acc[i], 32);
    }
    const float invL = 1.0f / l;
    if (g == 0) {  // lanes 0..7 write dims [dl, dl+8) of head h
        float4 o1 = {acc[0] * invL, acc[1] * invL, acc[2] * invL, acc[3] * invL};
        float4 o2 = {acc[4] * invL, acc[5] * invL, acc[6] * invL, acc[7] * invL};
        float* dst = attended + (size_t)n * HH + h * HID + dl;
        *reinterpret_cast<float4*>(dst)     = o1;
        *reinterpret_cast<float4*>(dst + 4) = o2;
    }
}

// ---------------------------------------------------------------------------
// post: 4 nodes per block (1024 blocks). W_out GEMV: all 256 threads, each
// computing 4 nodes' partials over its 128-d slice (W_out load amortized
// 4x). Then wave wv owns node wv's norm/xn/classifier.
// ---------------------------------------------------------------------------
__global__ __launch_bounds__(256) void post_kernel(
    const float* __restrict__ attended,
    const float* __restrict__ W_out, const float* __restrict__ b_out,
    const float* __restrict__ W_c1, const float* __restrict__ b_c1,
    const float* __restrict__ W_c2, const float* __restrict__ b_c2,
    float* __restrict__ scores, float* __restrict__ xn) {
    __shared__ float qv2[4][HH];     // 8KB: 4 attended rows
    __shared__ float red[4][256];    // 4KB
    __shared__ float nsbuf[4][HID];  // 1KB
    const int n0 = blockIdx.x * 4, t = threadIdx.x;
    const int wv = t >> 6, lane = t & 63;

    #pragma unroll
    for (int nd = 0; nd < 4; ++nd) {
        qv2[nd][t]       = attended[(size_t)(n0 + nd) * HH + t];
        qv2[nd][t + 256] = attended[(size_t)(n0 + nd) * HH + t + 256];
    }
    __syncthreads();

    const int j = t & 63, part = t >> 6;
    float p0 = 0.f, p1 = 0.f, p2 = 0.f, p3 = 0.f;
    for (int d = part * 128; d < part * 128 + 128; ++d) {
        const float w = W_out[d * HID + j];
        p0 += qv2[0][d] * w; p1 += qv2[1][d] * w;
        p2 += qv2[2][d] * w; p3 += qv2[3][d] * w;
    }
    red[0][t] = p0; red[1][t] = p1; red[2][t] = p2; red[3][t] = p3;
    __syncthreads();
    if (wv < 4 && lane < HID) {
        nsbuf[wv][lane] = red[wv][lane] + red[wv][lane + 64] +
                          red[wv][lane + 128] + red[wv][lane + 192] + b_out[lane];
    }
    __syncthreads();

    const int n = n0 + wv;
    const float ns = nsbuf[wv][lane];
    const float s2 = wave_reduce64(ns * ns);
    const float invn = 1.0f / fmaxf(sqrtf(s2), 1e-8f);
    xn[(size_t)n * HID + lane] = ns * invn;
    const float gb = gelu_exact(ns);  // concat-with-zeros half dead: gelu(0)=0
    __syncthreads();
    nsbuf[wv][lane] = gb;
    float hv = b_c1[lane];
    for (int i = 0; i < HID; ++i) hv += nsbuf[wv][i] * W_c1[i * HID + lane];
    const float hb = gelu_exact(hv);
    const float sc_ = wave_reduce64(hb * W_c2[lane]);
    if (lane == 0) scores[n] = sc_ + b_c2[0];
}

// ---------------------------------------------------------------------------
// Heatmap from CSR: wave-per-neighbor cosine dots, zero+scatter in LDS,
// nontemporal float4 row write (write-once 64MB, keep out of L2).
// ---------------------------------------------------------------------------
__global__ __launch_bounds__(256, 8) void heat_kernel(
    const unsigned short* __restrict__ nbr_g, const int* __restrict__ deg_g,
    const float* __restrict__ xn, float* __restrict__ heat) {
    __shared__ float srow[NN];          // 16KB
    __shared__ float simv[DMAX];
    __shared__ unsigned short nl[DMAX];
    __shared__ float inv_s;
    const int n = blockIdx.x, t = threadIdx.x;
    const int wv = t >> 6, lane = t & 63;
    const int deg = deg_g[n];

    float4* sr4 = (float4*)srow;
    const float4 z4 = {0.f, 0.f, 0.f, 0.f};
    for (int i = t; i < NN / 4; i += 256) sr4[i] = z4;
    if (t < deg) nl[t] = nbr_g[(size_t)n * DMAX + t];
    const float xq = xn[(size_t)n * HID + lane];
    __syncthreads();

    for (int c = wv; c < deg; c += 4) {
        const int m = nl[c];
        float s = wave_reduce64(xq * xn[(size_t)m * HID + lane]);
        if (lane == 0) { srow[m] = s; simv[c] = s; }
    }
    __syncthreads();
    if (t < 64) {
        float ps = 0.0f;
        for (int c = t; c < deg; c += 64) ps += simv[c];
        ps = wave_reduce64(ps);
        if (t == 0) inv_s = 1.0f / (ps + 1e-8f);
    }
    __syncthreads();
    const float inv = inv_s;
    vfloat4* hr4 = (vfloat4*)(heat + (size_t)n * NN);
    for (int i = t; i < NN / 4; i += 256) {
        float4 v = sr4[i];
        vfloat4 nv = {v.x * inv, v.y * inv, v.z * inv, v.w * inv};
        __builtin_nontemporal_store(nv, hr4 + i);
    }
}

// ---------------------------------------------------------------------------
extern "C" void kernel_launch(void* const* d_in, const int* in_sizes, int n_in,
                              void* d_out, int out_size, void* d_ws, size_t ws_size,
                              hipStream_t stream) {
    const float* features = (const float*)d_in[0];
    const void*  adj      = d_in[1];
    const float* W_in     = (const float*)d_in[2];
    const float* W_out    = (const float*)d_in[3];
    const float* b_out    = (const float*)d_in[4];
    const float* W_c1     = (const float*)d_in[5];
    const float* b_c1     = (const float*)d_in[6];
    const float* W_c2     = (const float*)d_in[7];
    const float* b_c2     = (const float*)d_in[8];

    float* scores = (float*)d_out;
    float* heat   = (float*)d_out + NN;

    // ws: projT 8MB | attended 8MB | xn 1MB | nbr_g 2MB | deg 16KB
    float*          projT    = (float*)d_ws;
    float*          attended = projT + (size_t)HEADS * NN * HID;
    float*          xn       = attended + (size_t)NN * HH;
    unsigned short* nbr_g    = (unsigned short*)(xn + (size_t)NN * HID);
    int*            deg_g    = (int*)(nbr_g + (size_t)NN * DMAX);

    prep_kernel<<<PROJ_BLOCKS + NN, 256, 0, stream>>>(adj, features, W_in,
                                                      projT, nbr_g, deg_g);
    attn_kernel<<<NN * HEADS / 4, 256, 0, stream>>>(projT, nbr_g, deg_g, attended);
    post_kernel<<<NN / 4, 256, 0, stream>>>(attended, W_out, b_out, W_c1, b_c1,
                                            W_c2, b_c2, scores, xn);
    heat_kernel<<<NN, 256, 0, stream>>>(nbr_g, deg_g, xn, heat);
}

// Round 14
// 215.375 us; speedup vs baseline: 1.2333x; 1.2333x over previous
//
#include <hip/hip_runtime.h>
#include <math.h>

constexpr int NN    = 4096;
constexpr int INDIM = 256;
constexpr int HID   = 64;
constexpr int HEADS = 8;
constexpr int HH    = HID * HEADS;  // 512
constexpr int DMAX  = 256;          // deg cap: Binomial(4096,0.01) mean 42
constexpr int PROJ_BLOCKS = 1024;   // 8 heads x 128 thirty-two-row tiles

typedef float        vfloat4 __attribute__((ext_vector_type(4)));
typedef unsigned int vuint4  __attribute__((ext_vector_type(4)));

__device__ __forceinline__ float gelu_exact(float x) {
    return 0.5f * x * (1.0f + erff(x * 0.70710678118654752f));
}

__device__ __forceinline__ float wave_reduce64(float v) {
    v += __shfl_xor(v, 32); v += __shfl_xor(v, 16); v += __shfl_xor(v, 8);
    v += __shfl_xor(v, 4);  v += __shfl_xor(v, 2);  v += __shfl_xor(v, 1);
    return v;
}

// ---------------------------------------------------------------------------
// prep: grid-partitioned fusion of proj (blocks 0..1023) and detect+CSR
// (blocks 1024..5119).
// proj lessons: R13 (LDS-free) was L1-BW-bound at 16% VALU - B must stay in
// LDS. R12 (LDS, 512 blocks) was latency-bound at 2 blocks/CU. This round:
// R12's inner loop with 32-row tiles -> 1024 blocks = 4 blocks/CU = 16
// waves/CU for latency hiding, B panel still LDS (32KB), A global->regs.
// Per 4-k step: 2 A-loads + 4 ds_read_b128 + 32 FMA (64cy VALU vs 48cy LDS).
// ---------------------------------------------------------------------------
__global__ __launch_bounds__(256) void prep_kernel(
    const void* __restrict__ adjv,
    const float* __restrict__ A, const float* __restrict__ B,
    float* __restrict__ projT,
    unsigned short* __restrict__ nbr_g, int* __restrict__ deg_g) {
    __shared__ float Bs[128][64];   // 32KB (proj path)
    __shared__ int wsum[4], u8w[4]; // csr path
    const int pb = blockIdx.x, t = threadIdx.x;
    const int wv = t >> 6, lane = t & 63;

    if (pb < PROJ_BLOCKS) {
        // ================= proj path =================
        const int bx = pb & 7;          // head (round-robin -> XCD-pinned)
        const int by = pb >> 3;         // 32-row tile (0..127)
        const int tx = t & 15, ty = t >> 4;
        const float* ap0 = A + (size_t)(by * 32 + ty * 2 + 0) * INDIM;
        const float* ap1 = A + (size_t)(by * 32 + ty * 2 + 1) * INDIM;
        float acc[2][4] = {{0.0f}};

        for (int kh = 0; kh < 2; ++kh) {
            // stage B half-panel: 128 k x 64 cols = 2048 float4, coalesced
            #pragma unroll
            for (int i = t; i < 128 * 16; i += 256) {
                const int k = i >> 4, c4 = (i & 15) * 4;
                *reinterpret_cast<float4*>(&Bs[k][c4]) =
                    *reinterpret_cast<const float4*>(
                        B + (size_t)(kh * 128 + k) * HH + bx * 64 + c4);
            }
            __syncthreads();
            #pragma unroll 2
            for (int k = 0; k < 128; k += 4) {
                const int ka = kh * 128 + k;
                const float4 av0 = *reinterpret_cast<const float4*>(ap0 + ka);
                const float4 av1 = *reinterpret_cast<const float4*>(ap1 + ka);
                float4 bv[4];
                #pragma unroll
                for (int kk = 0; kk < 4; ++kk)
                    bv[kk] = *reinterpret_cast<const float4*>(&Bs[k + kk][tx * 4]);
                acc[0][0] += av0.x * bv[0].x + av0.y * bv[1].x + av0.z * bv[2].x + av0.w * bv[3].x;
                acc[0][1] += av0.x * bv[0].y + av0.y * bv[1].y + av0.z * bv[2].y + av0.w * bv[3].y;
                acc[0][2] += av0.x * bv[0].z + av0.y * bv[1].z + av0.z * bv[2].z + av0.w * bv[3].z;
                acc[0][3] += av0.x * bv[0].w + av0.y * bv[1].w + av0.z * bv[2].w + av0.w * bv[3].w;
                acc[1][0] += av1.x * bv[0].x + av1.y * bv[1].x + av1.z * bv[2].x + av1.w * bv[3].x;
                acc[1][1] += av1.x * bv[0].y + av1.y * bv[1].y + av1.z * bv[2].y + av1.w * bv[3].y;
                acc[1][2] += av1.x * bv[0].z + av1.y * bv[1].z + av1.z * bv[2].z + av1.w * bv[3].z;
                acc[1][3] += av1.x * bv[0].w + av1.y * bv[1].w + av1.z * bv[2].w + av1.w * bv[3].w;
            }
            __syncthreads();
        }
        // projT[head=bx][node][dim]
        #pragma unroll
        for (int i = 0; i < 2; ++i) {
            float4 o = {acc[i][0], acc[i][1], acc[i][2], acc[i][3]};
            *reinterpret_cast<float4*>(
                projT + ((size_t)bx * NN + by * 32 + ty * 2 + i) * HID + tx * 4) = o;
        }
    } else {
        // ================= detect + csr path =================
        const int n = pb - PROJ_BLOCKS;
        // dtype detection on the buffer's first 4KB (identical bytes for
        // every block -> deterministic outcome)
        const vuint4 pw = __builtin_nontemporal_load(
            reinterpret_cast<const vuint4*>(adjv) + t);
        int u8loc = 0;
        #pragma unroll
        for (int a = 0; a < 4; ++a) {
            const unsigned w = pw[a];
            if (((w & ~0x01010101u) == 0u) && ((w & 0xFFFFFF00u) != 0u)) u8loc = 1;
        }
        const unsigned long long wb = __ballot(u8loc);
        if (lane == 0) u8w[wv] = (wb != 0ull);
        __syncthreads();
        const bool isU8 = (u8w[0] | u8w[1] | u8w[2] | u8w[3]) != 0;

        unsigned int nzmask = 0;  // bit j = element 16t+j of row n nonzero
        if (isU8) {
            const vuint4 r = __builtin_nontemporal_load(
                reinterpret_cast<const vuint4*>(
                    (const unsigned char*)adjv + (size_t)n * NN + 16 * t));
            #pragma unroll
            for (int a = 0; a < 4; ++a)
                #pragma unroll
                for (int j = 0; j < 4; ++j)
                    if ((r[a] >> (8 * j)) & 0xFFu) nzmask |= 1u << (a * 4 + j);
        } else {
            const vuint4* p = reinterpret_cast<const vuint4*>(
                (const unsigned int*)adjv + (size_t)n * NN + 16 * t);
            #pragma unroll
            for (int a = 0; a < 4; ++a) {
                const vuint4 r = __builtin_nontemporal_load(p + a);
                if (r[0]) nzmask |= 1u << (a * 4 + 0);
                if (r[1]) nzmask |= 1u << (a * 4 + 1);
                if (r[2]) nzmask |= 1u << (a * 4 + 2);
                if (r[3]) nzmask |= 1u << (a * 4 + 3);
            }
        }
        const int c = __popc(nzmask);
        int x = c;  // wave-inclusive prefix scan
        #pragma unroll
        for (int d = 1; d < 64; d <<= 1) {
            int y = __shfl_up(x, d);
            if (lane >= d) x += y;
        }
        if (lane == 63) wsum[wv] = x;
        __syncthreads();
        int base = 0;
        #pragma unroll
        for (int i = 0; i < 4; ++i)
            if (i < wv) base += wsum[i];
        const int deg = min(wsum[0] + wsum[1] + wsum[2] + wsum[3], DMAX);
        if (t == 0) deg_g[n] = deg;
        int o = base + x - c;
        unsigned int mm = nzmask;
        while (mm) {
            const int j = __ffs(mm) - 1;
            mm &= mm - 1;
            if (o < DMAX) nbr_g[(size_t)n * DMAX + o] = (unsigned short)(16 * t + j);
            ++o;
        }
    }
}

// ---------------------------------------------------------------------------
// Head-split sparse GAT attention. Block b: head = b&7 (round-robin dispatch
// over 8 XCDs -> each XCD gathers from ONE head's 1MB table, L2-resident),
// 4 nodes (one per wave). Group g=lane>>3 handles neighbors c0+g; dims
// dl=8*(lane&7).. No-max softmax (logits bounded, rows ~N(0,1)).
// ---------------------------------------------------------------------------
__global__ __launch_bounds__(256) void attn_kernel(
    const float* __restrict__ projT,
    const unsigned short* __restrict__ nbr_g, const int* __restrict__ deg_g,
    float* __restrict__ attended) {
    __shared__ unsigned short nl[4][DMAX];   // 2KB: per-wave CSR row
    const int b = blockIdx.x, t = threadIdx.x;
    const int wv = t >> 6, lane = t & 63;
    const int h = b & 7;
    const int n = (b >> 3) * 4 + wv;
    const int deg = deg_g[n];

    *reinterpret_cast<ushort4*>(&nl[wv][lane * 4]) =
        *reinterpret_cast<const ushort4*>(nbr_g + (size_t)n * DMAX + lane * 4);

    const float* tab = projT + (size_t)h * NN * HID;
    const int g = lane >> 3, dl = (lane & 7) * 8;

    float q[8];
    {
        const float4 a = *reinterpret_cast<const float4*>(tab + (size_t)n * HID + dl);
        const float4 bq = *reinterpret_cast<const float4*>(tab + (size_t)n * HID + dl + 4);
        q[0] = a.x;  q[1] = a.y;  q[2] = a.z;  q[3] = a.w;
        q[4] = bq.x; q[5] = bq.y; q[6] = bq.z; q[7] = bq.w;
    }

    float l = 0.0f;
    float acc[8] = {0.f, 0.f, 0.f, 0.f, 0.f, 0.f, 0.f, 0.f};
    for (int c0 = 0; c0 < deg; c0 += 8) {
        const int c = c0 + g;
        const int idx = nl[wv][min(c, deg - 1)];
        const float* kp = tab + (size_t)idx * HID + dl;
        const float4 ka = *reinterpret_cast<const float4*>(kp);
        const float4 kb = *reinterpret_cast<const float4*>(kp + 4);
        float kf[8] = {ka.x, ka.y, ka.z, ka.w, kb.x, kb.y, kb.z, kb.w};
        float s = q[0]*kf[0] + q[1]*kf[1] + q[2]*kf[2] + q[3]*kf[3] +
                  q[4]*kf[4] + q[5]*kf[5] + q[6]*kf[6] + q[7]*kf[7];
        s += __shfl_xor(s, 1); s += __shfl_xor(s, 2); s += __shfl_xor(s, 4);
        const float w = (c < deg) ? expf(s * 0.125f) : 0.0f;  // 1/sqrt(64)
        l += w;
        #pragma unroll
        for (int i = 0; i < 8; ++i) acc[i] += w * kf[i];
    }
    l += __shfl_xor(l, 8); l += __shfl_xor(l, 16); l += __shfl_xor(l, 32);
    #pragma unroll
    for (int i = 0; i < 8; ++i) {
        acc[i] += __shfl_xor(acc[i], 8);
        acc[i] += __shfl_xor(acc[i], 16);
        acc[i] += __shfl_xor(acc[i], 32);
    }
    const float invL = 1.0f / l;
    if (g == 0) {  // lanes 0..7 write dims [dl, dl+8) of head h
        float4 o1 = {acc[0] * invL, acc[1] * invL, acc[2] * invL, acc[3] * invL};
        float4 o2 = {acc[4] * invL, acc[5] * invL, acc[6] * invL, acc[7] * invL};
        float* dst = attended + (size_t)n * HH + h * HID + dl;
        *reinterpret_cast<float4*>(dst)     = o1;
        *reinterpret_cast<float4*>(dst + 4) = o2;
    }
}

// ---------------------------------------------------------------------------
// post: 4 nodes per block (1024 blocks). W_out GEMV: all 256 threads, each
// computing 4 nodes' partials over its 128-d slice (W_out load amortized
// 4x). Then wave wv owns node wv's norm/xn/classifier.
// ---------------------------------------------------------------------------
__global__ __launch_bounds__(256) void post_kernel(
    const float* __restrict__ attended,
    const float* __restrict__ W_out, const float* __restrict__ b_out,
    const float* __restrict__ W_c1, const float* __restrict__ b_c1,
    const float* __restrict__ W_c2, const float* __restrict__ b_c2,
    float* __restrict__ scores, float* __restrict__ xn) {
    __shared__ float qv2[4][HH];     // 8KB: 4 attended rows
    __shared__ float red[4][256];    // 4KB
    __shared__ float nsbuf[4][HID];  // 1KB
    const int n0 = blockIdx.x * 4, t = threadIdx.x;
    const int wv = t >> 6, lane = t & 63;

    #pragma unroll
    for (int nd = 0; nd < 4; ++nd) {
        qv2[nd][t]       = attended[(size_t)(n0 + nd) * HH + t];
        qv2[nd][t + 256] = attended[(size_t)(n0 + nd) * HH + t + 256];
    }
    __syncthreads();

    const int j = t & 63, part = t >> 6;
    float p0 = 0.f, p1 = 0.f, p2 = 0.f, p3 = 0.f;
    for (int d = part * 128; d < part * 128 + 128; ++d) {
        const float w = W_out[d * HID + j];
        p0 += qv2[0][d] * w; p1 += qv2[1][d] * w;
        p2 += qv2[2][d] * w; p3 += qv2[3][d] * w;
    }
    red[0][t] = p0; red[1][t] = p1; red[2][t] = p2; red[3][t] = p3;
    __syncthreads();
    if (wv < 4 && lane < HID) {
        nsbuf[wv][lane] = red[wv][lane] + red[wv][lane + 64] +
                          red[wv][lane + 128] + red[wv][lane + 192] + b_out[lane];
    }
    __syncthreads();

    const int n = n0 + wv;
    const float ns = nsbuf[wv][lane];
    const float s2 = wave_reduce64(ns * ns);
    const float invn = 1.0f / fmaxf(sqrtf(s2), 1e-8f);
    xn[(size_t)n * HID + lane] = ns * invn;
    const float gb = gelu_exact(ns);  // concat-with-zeros half dead: gelu(0)=0
    __syncthreads();
    nsbuf[wv][lane] = gb;
    float hv = b_c1[lane];
    for (int i = 0; i < HID; ++i) hv += nsbuf[wv][i] * W_c1[i * HID + lane];
    const float hb = gelu_exact(hv);
    const float sc_ = wave_reduce64(hb * W_c2[lane]);
    if (lane == 0) scores[n] = sc_ + b_c2[0];
}

// ---------------------------------------------------------------------------
// Heatmap from CSR: wave-per-neighbor cosine dots, zero+scatter in LDS,
// nontemporal float4 row write (write-once 64MB, keep out of L2).
// ---------------------------------------------------------------------------
__global__ __launch_bounds__(256, 8) void heat_kernel(
    const unsigned short* __restrict__ nbr_g, const int* __restrict__ deg_g,
    const float* __restrict__ xn, float* __restrict__ heat) {
    __shared__ float srow[NN];          // 16KB
    __shared__ float simv[DMAX];
    __shared__ unsigned short nl[DMAX];
    __shared__ float inv_s;
    const int n = blockIdx.x, t = threadIdx.x;
    const int wv = t >> 6, lane = t & 63;
    const int deg = deg_g[n];

    float4* sr4 = (float4*)srow;
    const float4 z4 = {0.f, 0.f, 0.f, 0.f};
    for (int i = t; i < NN / 4; i += 256) sr4[i] = z4;
    if (t < deg) nl[t] = nbr_g[(size_t)n * DMAX + t];
    const float xq = xn[(size_t)n * HID + lane];
    __syncthreads();

    for (int c = wv; c < deg; c += 4) {
        const int m = nl[c];
        float s = wave_reduce64(xq * xn[(size_t)m * HID + lane]);
        if (lane == 0) { srow[m] = s; simv[c] = s; }
    }
    __syncthreads();
    if (t < 64) {
        float ps = 0.0f;
        for (int c = t; c < deg; c += 64) ps += simv[c];
        ps = wave_reduce64(ps);
        if (t == 0) inv_s = 1.0f / (ps + 1e-8f);
    }
    __syncthreads();
    const float inv = inv_s;
    vfloat4* hr4 = (vfloat4*)(heat + (size_t)n * NN);
    for (int i = t; i < NN / 4; i += 256) {
        float4 v = sr4[i];
        vfloat4 nv = {v.x * inv, v.y * inv, v.z * inv, v.w * inv};
        __builtin_nontemporal_store(nv, hr4 + i);
    }
}

// ---------------------------------------------------------------------------
extern "C" void kernel_launch(void* const* d_in, const int* in_sizes, int n_in,
                              void* d_out, int out_size, void* d_ws, size_t ws_size,
                              hipStream_t stream) {
    const float* features = (const float*)d_in[0];
    const void*  adj      = d_in[1];
    const float* W_in     = (const float*)d_in[2];
    const float* W_out    = (const float*)d_in[3];
    const float* b_out    = (const float*)d_in[4];
    const float* W_c1     = (const float*)d_in[5];
    const float* b_c1     = (const float*)d_in[6];
    const float* W_c2     = (const float*)d_in[7];
    const float* b_c2     = (const float*)d_in[8];

    float* scores = (float*)d_out;
    float* heat   = (float*)d_out + NN;

    // ws: projT 8MB | attended 8MB | xn 1MB | nbr_g 2MB | deg 16KB
    float*          projT    = (float*)d_ws;
    float*          attended = projT + (size_t)HEADS * NN * HID;
    float*          xn       = attended + (size_t)NN * HH;
    unsigned short* nbr_g    = (unsigned short*)(xn + (size_t)NN * HID);
    int*            deg_g    = (int*)(nbr_g + (size_t)NN * DMAX);

    prep_kernel<<<PROJ_BLOCKS + NN, 256, 0, stream>>>(adj, features, W_in,
                                                      projT, nbr_g, deg_g);
    attn_kernel<<<NN * HEADS / 4, 256, 0, stream>>>(projT, nbr_g, deg_g, attended);
    post_kernel<<<NN / 4, 256, 0, stream>>>(attended, W_out, b_out, W_c1, b_c1,
                                            W_c2, b_c2, scores, xn);
    heat_kernel<<<NN, 256, 0, stream>>>(nbr_g, deg_g, xn, heat);
}